// Round 7
// baseline (4889.514 us; speedup 1.0000x reference)
//
#include <hip/hip_runtime.h>
#include <stdint.h>

#define BATCH 4
#define NPTS  8192
#define CFEAT 64
#define MCENT 2048
#define NCENT (BATCH * MCENT)
#define KMAX  64
#define NEGV  -1e30f

// Exact-rounding squared distance, matching numpy's ((dx*dx+dy*dy)+dz*dz)
// with NO fma contraction (discrete neighbor selection requires bit parity).
__device__ __forceinline__ float dist2(float ax, float ay, float az,
                                       float bx, float by, float bz) {
    float dx = __fsub_rn(ax, bx);
    float dy = __fsub_rn(ay, by);
    float dz = __fsub_rn(az, bz);
    return __fadd_rn(__fadd_rn(__fmul_rn(dx, dx), __fmul_rn(dy, dy)),
                     __fmul_rn(dz, dz));
}

// DPP lane-permute helpers (VALU-latency cross-lane)
template <int CTRL>
__device__ __forceinline__ float dppf(float v) {
    return __int_as_float(__builtin_amdgcn_update_dpp(
        __float_as_int(v), __float_as_int(v), CTRL, 0xF, 0xF, false));
}
template <int CTRL>
__device__ __forceinline__ int dppi(int v) {
    return __builtin_amdgcn_update_dpp(v, v, CTRL, 0xF, 0xF, false);
}

// ---------------------------------------------------------------------------
// Kernel 1: spatially-pruned farthest point sampling. One block/batch, 512
// threads. Round-6 post-mortem: full re-scan of the cloud every iteration
// costs >=768 cyc LDS + ~900 cyc VALU issue -- but after ~150 iters only ~2%
// of points can change (new centroid lowers mind only within ~sqrt(mind)).
// Structure: 8x8x8 grid in LDS (reordered coords, mind, orig idx, per-cell
// max(mind)). Per iter: (A) per-cell box lower bound, prune if
// lb2*0.9999 >= cellmax (deflation = conservative under fp rounding: skip
// only provably-no-op cells); ballot-compact survivors; (B) one wave per
// surviving cell updates mind exactly + DPP-max -> cellmax (full float4 pass
// if NU>192, early iters); (C) block argmax over cellmax, wave 0 locates the
// point (tie -> lowest ORIGINAL index within the cell). mind arithmetic is
// bit-identical to the unpruned version.
// ---------------------------------------------------------------------------
#define FPS_T      512
#define NCELL      512
#define FPS_THRESH 192

__global__ __launch_bounds__(FPS_T, 1) void fps_kernel(const float* __restrict__ pos,
                                                       float* __restrict__ pos_s) {
    const int b = blockIdx.x;
    const float* pb = pos + b * NPTS * 3;
    const int t = threadIdx.x;          // 0..511 (== cell id in per-cell phases)
    const int w = t >> 6;               // wave id 0..7
    const int l = t & 63;               // lane id

    __shared__ __align__(16) float rx[NPTS];
    __shared__ __align__(16) float ry[NPTS];
    __shared__ __align__(16) float rz[NPTS];
    __shared__ __align__(16) float smind[NPTS];
    __shared__ unsigned short sridx[NPTS];
    __shared__ int   cellstart[NCELL + 1];
    __shared__ int   coff[NCELL];
    __shared__ float cellmax[NCELL];
    __shared__ int   clist[NCELL];
    __shared__ float s_bv[8];
    __shared__ int   s_bc[8];
    __shared__ int   s_nu;
    __shared__ float s_winx, s_winy, s_winz;

    // ---------------- setup: histogram -> prefix -> scatter ----------------
    coff[t] = 0;
    __syncthreads();
    for (int i = 0; i < 16; ++i) {
        int p = (i << 9) + t;
        float xx = pb[3 * p + 0], yy = pb[3 * p + 1], zz = pb[3 * p + 2];
        int ix = min((int)(xx * 8.0f), 7);   // clamp: x just below 1.0 can
        int iy = min((int)(yy * 8.0f), 7);   // round x*8 up to 8.0
        int iz = min((int)(zz * 8.0f), 7);
        atomicAdd(&coff[(iz << 6) | (iy << 3) | ix], 1);
    }
    __syncthreads();
    if (t == 0) {
        int acc = 0;
        for (int q = 0; q < NCELL; ++q) { cellstart[q] = acc; acc += coff[q]; }
        cellstart[NCELL] = acc;
        s_nu = 0;
    }
    __syncthreads();
    coff[t] = 0;
    __syncthreads();
    for (int i = 0; i < 16; ++i) {
        int p = (i << 9) + t;
        float xx = pb[3 * p + 0], yy = pb[3 * p + 1], zz = pb[3 * p + 2];
        int ix = min((int)(xx * 8.0f), 7);
        int iy = min((int)(yy * 8.0f), 7);
        int iz = min((int)(zz * 8.0f), 7);
        int cid = (iz << 6) | (iy << 3) | ix;
        int slot = cellstart[cid] + atomicAdd(&coff[cid], 1);
        rx[slot] = xx; ry[slot] = yy; rz[slot] = zz;
        sridx[slot] = (unsigned short)p;
        smind[slot] = 1e30f;
    }
    cellmax[t] = 1e30f;
    // this thread's cell box (multiples of 0.125 are exact in fp32)
    const float lox = (float)(t & 7) * 0.125f;
    const float loy = (float)((t >> 3) & 7) * 0.125f;
    const float loz = (float)(t >> 6) * 0.125f;
    __syncthreads();

    float lx = pb[0], ly = pb[1], lz = pb[2];   // first centroid = point 0

    for (int m = 0; m < MCENT; ++m) {
        if (t == 0) {
            float* o = pos_s + (b * MCENT + m) * 3;
            o[0] = lx; o[1] = ly; o[2] = lz;
        }
        if (m + 1 == MCENT) break;      // final argmax discarded by the scan

        // ---- A: per-cell lower bound + prune + ballot-compact survivors
        float dxm = fmaxf(fmaxf(lox - lx, lx - (lox + 0.125f)), 0.0f);
        float dym = fmaxf(fmaxf(loy - ly, ly - (loy + 0.125f)), 0.0f);
        float dzm = fmaxf(fmaxf(loz - lz, lz - (loz + 0.125f)), 0.0f);
        float lb2 = fmaf(dxm, dxm, fmaf(dym, dym, dzm * dzm)) * 0.9999f;
        bool sv = lb2 < cellmax[t];
        unsigned long long mk = __ballot(sv);
        int base = 0;
        if (l == 0 && mk) base = atomicAdd(&s_nu, __popcll(mk));
        base = __shfl(base, 0);
        if (sv) clist[base + __popcll(mk & ((1ull << l) - 1ull))] = t;
        __syncthreads();                                    // b1
        const int NU = s_nu;

        if (NU > FPS_THRESH) {
            // ---- B-full: update all points (float4-wide), then all cellmax
            for (int i = 0; i < 4; ++i) {
                int g = (i << 9) + t;
                float4 fx = ((const float4*)rx)[g];
                float4 fy = ((const float4*)ry)[g];
                float4 fz = ((const float4*)rz)[g];
                float4 fm = ((const float4*)smind)[g];
                fm.x = fminf(fm.x, dist2(fx.x, fy.x, fz.x, lx, ly, lz));
                fm.y = fminf(fm.y, dist2(fx.y, fy.y, fz.y, lx, ly, lz));
                fm.z = fminf(fm.z, dist2(fx.z, fy.z, fz.z, lx, ly, lz));
                fm.w = fminf(fm.w, dist2(fx.w, fy.w, fz.w, lx, ly, lz));
                ((float4*)smind)[g] = fm;
            }
            __syncthreads();
            int s0 = cellstart[t], e0 = cellstart[t + 1];
            float red = -1.0f;
            for (int j = s0; j < e0; ++j) red = fmaxf(red, smind[j]);
            cellmax[t] = red;
        } else {
            // ---- B-sparse: one wave per surviving cell
            int rounds = (NU + 7) >> 3;
            for (int r = 0; r < rounds; ++r) {
                int u = (r << 3) + w;
                if (u < NU) {                       // wave-uniform branch
                    int cid = clist[u];
                    int s0 = cellstart[cid], e0 = cellstart[cid + 1];
                    float red = -1.0f;
                    for (int j = s0 + l; j < e0; j += 64) {
                        float d = dist2(rx[j], ry[j], rz[j], lx, ly, lz);
                        float mn = fminf(smind[j], d);
                        smind[j] = mn;
                        red = fmaxf(red, mn);
                    }
#define MSTEP(C_) { float ov = dppf<C_>(red); red = fmaxf(red, ov); }
                    MSTEP(0xB1) MSTEP(0x4E) MSTEP(0x141)
                    MSTEP(0x140) MSTEP(0x142) MSTEP(0x143)
#undef MSTEP
                    if (l == 63) cellmax[cid] = red;
                }
            }
        }
        __syncthreads();                                    // b2

        // ---- C: block argmax over cellmax (tie -> lower cell id)
        float bv = cellmax[t]; int bc = t;
#define RSTEP(C_) { float ov = dppf<C_>(bv); int oc = dppi<C_>(bc);           \
                    bool tk = (ov > bv) || (ov == bv && oc < bc);             \
                    bv = tk ? ov : bv; bc = tk ? oc : bc; }
        RSTEP(0xB1) RSTEP(0x4E) RSTEP(0x141)
        RSTEP(0x140) RSTEP(0x142) RSTEP(0x143)
#undef RSTEP
        if (l == 63) { s_bv[w] = bv; s_bc[w] = bc; }
        __syncthreads();                                    // b3
        float gv = s_bv[0]; int gc = s_bc[0];
#pragma unroll
        for (int q = 1; q < 8; ++q) {
            float ov = s_bv[q]; int oc = s_bc[q];
            bool tk = (ov > gv) || (ov == gv && oc < gc);
            gv = tk ? ov : gv; gc = tk ? oc : gc;
        }
        // locate the winner inside cell gc (tie -> lowest ORIGINAL index)
        if (w == 0) {
            int s0 = cellstart[gc], e0 = cellstart[gc + 1];
            int best = 0x7FFFFFFF;
            for (int j = s0 + l; j < e0; j += 64) {
                if (smind[j] == gv)
                    best = min(best, (((int)sridx[j]) << 13) | j);
            }
#define NSTEP(C_) { int o = dppi<C_>(best); best = min(best, o); }
            NSTEP(0xB1) NSTEP(0x4E) NSTEP(0x141)
            NSTEP(0x140) NSTEP(0x142) NSTEP(0x143)
#undef NSTEP
            if (l == 63) {
                int j = best & 8191;
                s_winx = rx[j]; s_winy = ry[j]; s_winz = rz[j];
            }
        }
        if (t == 0) s_nu = 0;
        __syncthreads();                                    // b4
        lx = s_winx; ly = s_winy; lz = s_winz;
    }
}

// ---------------------------------------------------------------------------
// Kernel 2: exact top-64 (by (d2, idx) u64 key) within ball r=0.4 via
// histogram radix-select + O(C^2) exact ranking. (unchanged)
// ---------------------------------------------------------------------------
#define KNN_CAP 320

__global__ __launch_bounds__(256) void knn_kernel(const float* __restrict__ pos,
                                                  const float* __restrict__ pos_s,
                                                  int* __restrict__ nidx,
                                                  float* __restrict__ nd2,
                                                  int* __restrict__ ncnt) {
    const int c = blockIdx.x;
    const int b = c >> 11;              // c / MCENT
    const float* pb = pos + b * NPTS * 3;
    const int t = threadIdx.x;

    const float cx = pos_s[c * 3 + 0];
    const float cy = pos_s[c * 3 + 1];
    const float cz = pos_s[c * 3 + 2];

    __shared__ int hist[64];
    __shared__ int s_B64, s_total, s_cnt;
    __shared__ unsigned long long cand[KNN_CAP];

    if (t < 64) hist[t] = 0;
    if (t == 0) s_cnt = 0;
    __syncthreads();

    float d2r[32];
#pragma unroll
    for (int i = 0; i < 32; ++i) {
        int p = (i << 8) + t;
        float d2 = dist2(cx, cy, cz, pb[3 * p + 0], pb[3 * p + 1], pb[3 * p + 2]);
        d2r[i] = d2;
        if (d2 <= 0.16f) {
            int bkt = (int)(d2 * 400.0f);      // monotone; 0.16f*400 < 64
            bkt = bkt > 63 ? 63 : bkt;
            atomicAdd(&hist[bkt], 1);
        }
    }
    __syncthreads();

    if (t == 0) {
        int cum = 0, B = -1;
#pragma unroll
        for (int j = 0; j < 64; ++j) {
            cum += hist[j];
            if (B < 0 && cum >= 64) B = j;
        }
        s_B64 = (B < 0) ? 63 : B;
        s_total = cum;
    }
    __syncthreads();

    const int B64 = s_B64;
#pragma unroll
    for (int i = 0; i < 32; ++i) {
        float d2 = d2r[i];
        if (d2 <= 0.16f) {
            int bkt = (int)(d2 * 400.0f);
            bkt = bkt > 63 ? 63 : bkt;
            if (bkt <= B64) {
                int slot = atomicAdd(&s_cnt, 1);
                if (slot < KNN_CAP) {
                    int p = (i << 8) + t;
                    cand[slot] = ((unsigned long long)__float_as_uint(d2) << 32)
                                 | (unsigned int)p;
                }
            }
        }
    }
    __syncthreads();

    const int C = s_cnt < KNN_CAP ? s_cnt : KNN_CAP;
    for (int tc = t; tc < C; tc += 256) {
        unsigned long long my = cand[tc];
        int rank = 0;
        for (int j = 0; j < C; ++j) rank += (cand[j] < my) ? 1 : 0;
        if (rank < KMAX) {
            nidx[c * KMAX + rank] = (int)(my & 0xffffffffULL);
            nd2[c * KMAX + rank]  = __uint_as_float((unsigned int)(my >> 32));
        }
    }
    if (t == 0) ncnt[c] = s_total < KMAX ? s_total : KMAX;
}

// ---------------------------------------------------------------------------
// Kernel 3: fused gather + 2-layer MLP + masked max per centroid. (unchanged)
// ---------------------------------------------------------------------------
template <int K, int C1, int C2, int OUTOFF>
__global__ __launch_bounds__(256, 2) void mlp_kernel(
        const float* __restrict__ x, const float* __restrict__ pos,
        const float* __restrict__ pos_s,
        const int* __restrict__ nidx, const float* __restrict__ nd2,
        const int* __restrict__ ncnt,
        const float* __restrict__ W1, const float* __restrict__ B1,
        const float* __restrict__ W2, const float* __restrict__ B2,
        float* __restrict__ out, float r2) {
    const int c = blockIdx.x;
    const int b = c >> 11;
    const int t = threadIdx.x;

    __shared__ float F[K][68];      // [K][67] padded to 17 float4
    __shared__ float H[K][C1];
    __shared__ int   s_nbr[K];
    __shared__ int   s_valid[K];
    __shared__ float s_ctr[3];

    const int cntAll = ncnt[c];
    const int cnt = cntAll < K ? cntAll : K;
    if (t < 3) s_ctr[t] = pos_s[c * 3 + t];
    if (t < K) {
        bool ok = t < cnt;
        s_nbr[t]   = ok ? nidx[c * KMAX + t] : 0;
        s_valid[t] = ok && (nd2[c * KMAX + t] <= r2);
    }
    __syncthreads();

    // gather features: F[k] = [ x[nbr] (64) | pos[nbr]-ctr (3) | 0 pad ]
    for (int e = t; e < K * 17; e += 256) {
        int k = e / 17, q = e % 17;
        int nbr = s_nbr[k];
        bool ok = k < cnt;
        float4 val;
        if (q < 16) {
            const float4* xr = (const float4*)(x + (b * NPTS + nbr) * CFEAT);
            if (ok) val = xr[q];
            else { val.x = 0.f; val.y = 0.f; val.z = 0.f; val.w = 0.f; }
        } else {
            const float* pp = pos + (b * NPTS + nbr) * 3;
            val.x = ok ? pp[0] - s_ctr[0] : 0.f;
            val.y = ok ? pp[1] - s_ctr[1] : 0.f;
            val.z = ok ? pp[2] - s_ctr[2] : 0.f;
            val.w = 0.f;
        }
        ((float4*)&F[k][0])[q] = val;
    }
    __syncthreads();

    // layer 1: H[k][j] = relu(B1[j] + F[k]·W1[:,j])
    {
        constexpr int STR = 256 / C1;
        const int j  = t % C1;
        const int kb = t / C1;
        float w1c[68];
#pragma unroll
        for (int i = 0; i < 67; ++i) w1c[i] = W1[i * C1 + j];
        w1c[67] = 0.f;
        const float bj = B1[j];
        for (int k = kb; k < K; k += STR) {
            float acc = bj;
            const float4* fr = (const float4*)&F[k][0];
#pragma unroll
            for (int q = 0; q < 17; ++q) {
                float4 f = fr[q];
                acc = fmaf(f.x, w1c[4 * q + 0], acc);
                acc = fmaf(f.y, w1c[4 * q + 1], acc);
                acc = fmaf(f.z, w1c[4 * q + 2], acc);
                acc = fmaf(f.w, w1c[4 * q + 3], acc);
            }
            H[k][j] = fmaxf(acc, 0.f);
        }
    }
    __syncthreads();

    // layer 2 + masked max over neighbors
    if constexpr (C2 == 256) {
        const int j2 = t;
        float w2c[C1];
#pragma unroll
        for (int i = 0; i < C1; ++i) w2c[i] = W2[i * C2 + j2];
        const float bj = B2[j2];
        float omax = NEGV;
        for (int k = 0; k < K; ++k) {
            if (!s_valid[k]) continue;          // uniform branch
            float acc = bj;
            const float4* hr = (const float4*)&H[k][0];
#pragma unroll
            for (int q = 0; q < C1 / 4; ++q) {
                float4 h = hr[q];
                acc = fmaf(h.x, w2c[4 * q + 0], acc);
                acc = fmaf(h.y, w2c[4 * q + 1], acc);
                acc = fmaf(h.z, w2c[4 * q + 2], acc);
                acc = fmaf(h.w, w2c[4 * q + 3], acc);
            }
            omax = fmaxf(omax, fmaxf(acc, 0.f));
        }
        out[c * 384 + OUTOFF + j2] = omax;
    } else {
        // C2 == 128: 2 thread-groups split the k range, combine via LDS
        const int j2 = t % C2;
        const int g  = t / C2;
        __shared__ float pm[256];
        float w2c[C1];
#pragma unroll
        for (int i = 0; i < C1; ++i) w2c[i] = W2[i * C2 + j2];
        const float bj = B2[j2];
        float omax = NEGV;
        for (int k = g; k < K; k += 2) {
            if (!s_valid[k]) continue;
            float acc = bj;
            const float4* hr = (const float4*)&H[k][0];
#pragma unroll
            for (int q = 0; q < C1 / 4; ++q) {
                float4 h = hr[q];
                acc = fmaf(h.x, w2c[4 * q + 0], acc);
                acc = fmaf(h.y, w2c[4 * q + 1], acc);
                acc = fmaf(h.z, w2c[4 * q + 2], acc);
                acc = fmaf(h.w, w2c[4 * q + 3], acc);
            }
            omax = fmaxf(omax, fmaxf(acc, 0.f));
        }
        pm[t] = omax;
        __syncthreads();
        if (t < C2) out[c * 384 + OUTOFF + t] = fmaxf(pm[t], pm[t + C2]);
    }
}

extern "C" void kernel_launch(void* const* d_in, const int* in_sizes, int n_in,
                              void* d_out, int out_size, void* d_ws, size_t ws_size,
                              hipStream_t stream) {
    const float* x    = (const float*)d_in[0];
    const float* pos  = (const float*)d_in[1];
    const float* w1_0 = (const float*)d_in[2];
    const float* b1_0 = (const float*)d_in[3];
    const float* w1_1 = (const float*)d_in[4];
    const float* b1_1 = (const float*)d_in[5];
    const float* w2_0 = (const float*)d_in[6];
    const float* b2_0 = (const float*)d_in[7];
    const float* w2_1 = (const float*)d_in[8];
    const float* b2_1 = (const float*)d_in[9];

    float* out   = (float*)d_out;
    float* pos_s = out + NCENT * 384;          // second output, written by FPS

    char* ws = (char*)d_ws;
    int*   ncnt = (int*)ws;                                   // NCENT ints
    int*   nidx = (int*)(ws + NCENT * 4);                     // NCENT*64 ints
    float* nd2  = (float*)(ws + NCENT * 4 + NCENT * KMAX * 4);// NCENT*64 floats

    fps_kernel<<<BATCH, FPS_T, 0, stream>>>(pos, pos_s);
    knn_kernel<<<NCENT, 256, 0, stream>>>(pos, pos_s, nidx, nd2, ncnt);
    mlp_kernel<32, 64, 128, 0><<<NCENT, 256, 0, stream>>>(
        x, pos, pos_s, nidx, nd2, ncnt, w1_0, b1_0, w1_1, b1_1, out, 0.04f);
    mlp_kernel<64, 128, 256, 128><<<NCENT, 256, 0, stream>>>(
        x, pos, pos_s, nidx, nd2, ncnt, w2_0, b2_0, w2_1, b2_1, out, 0.16f);
}

// Round 8
// 4530.829 us; speedup vs baseline: 1.0792x; 1.0792x over previous
//
#include <hip/hip_runtime.h>
#include <stdint.h>

#define BATCH 4
#define NPTS  8192
#define CFEAT 64
#define MCENT 2048
#define NCENT (BATCH * MCENT)
#define KMAX  64
#define NEGV  -1e30f

// Exact-rounding squared distance, matching numpy's ((dx*dx+dy*dy)+dz*dz)
// with NO fma contraction (discrete neighbor selection requires bit parity).
__device__ __forceinline__ float dist2(float ax, float ay, float az,
                                       float bx, float by, float bz) {
    float dx = __fsub_rn(ax, bx);
    float dy = __fsub_rn(ay, by);
    float dz = __fsub_rn(az, bz);
    return __fadd_rn(__fadd_rn(__fmul_rn(dx, dx), __fmul_rn(dy, dy)),
                     __fmul_rn(dz, dz));
}

// DPP lane-permute helpers (VALU-latency cross-lane)
template <int CTRL>
__device__ __forceinline__ float dppf(float v) {
    return __int_as_float(__builtin_amdgcn_update_dpp(
        __float_as_int(v), __float_as_int(v), CTRL, 0xF, 0xF, false));
}
template <int CTRL>
__device__ __forceinline__ int dppi(int v) {
    return __builtin_amdgcn_update_dpp(v, v, CTRL, 0xF, 0xF, false);
}

// ---------------------------------------------------------------------------
// Kernel 1: spatially-pruned FPS. Round-7 post-mortem: correct pruning but
// latency-serialized (whole wave per ~16-pt cell, 4 serial rounds, 4
// barriers, separate winner-search phase). Round-8 structure:
//   A: per-cell box lower bound vs cellmax (deflated conservative), ballot-
//      compact survivors (readfirstlane broadcast).                  [b1]
//   B: QUARTER-WAVE (16 lanes = 1 DPP row) per surviving cell -> 32
//      cells/round, NU~30 => 1 round. Computes per-cell (max, arg),
//      arg=(orig_idx<<13)|j  (exact jnp.argmax tie-break, even x-cell). [b2]
//   C: 512-entry block argmax of (cellmax, cellarg); winner coords = 3
//      broadcast LDS reads. No winner-search phase.                  [b3]
// Dense fallback (NU>128): float4 full update + per-cell rescan.
// mind arithmetic is bit-identical to the unpruned version; pruning skips
// only provably-no-op cells.
// ---------------------------------------------------------------------------
#define FPS_T      512
#define NCELL      512
#define FPS_THRESH 128

__global__ __launch_bounds__(FPS_T, 1) void fps_kernel(const float* __restrict__ pos,
                                                       float* __restrict__ pos_s) {
    const int b = blockIdx.x;
    const float* pb = pos + b * NPTS * 3;
    const int t = threadIdx.x;          // 0..511 (== cell id in per-cell phases)
    const int w = t >> 6;               // wave id 0..7
    const int l = t & 63;               // lane id

    __shared__ __align__(16) float rx[NPTS];
    __shared__ __align__(16) float ry[NPTS];
    __shared__ __align__(16) float rz[NPTS];
    __shared__ __align__(16) float smind[NPTS];
    __shared__ unsigned short sridx[NPTS];
    __shared__ int   cellstart[NCELL + 1];
    __shared__ int   coff[NCELL];
    __shared__ float cellmax[NCELL];
    __shared__ int   cellarg[NCELL];
    __shared__ int   clist[NCELL];
    __shared__ float s_bv[8];
    __shared__ int   s_ba[8];
    __shared__ int   s_nu;

    // ---------------- setup: histogram -> prefix -> scatter ----------------
    coff[t] = 0;
    __syncthreads();
    for (int i = 0; i < 16; ++i) {
        int p = (i << 9) + t;
        float xx = pb[3 * p + 0], yy = pb[3 * p + 1], zz = pb[3 * p + 2];
        int ix = min((int)(xx * 8.0f), 7);   // clamp: x just below 1.0 can
        int iy = min((int)(yy * 8.0f), 7);   // round x*8 up to 8.0
        int iz = min((int)(zz * 8.0f), 7);
        atomicAdd(&coff[(iz << 6) | (iy << 3) | ix], 1);
    }
    __syncthreads();
    if (t == 0) {
        int acc = 0;
        for (int q = 0; q < NCELL; ++q) { cellstart[q] = acc; acc += coff[q]; }
        cellstart[NCELL] = acc;
        s_nu = 0;
    }
    __syncthreads();
    coff[t] = 0;
    __syncthreads();
    for (int i = 0; i < 16; ++i) {
        int p = (i << 9) + t;
        float xx = pb[3 * p + 0], yy = pb[3 * p + 1], zz = pb[3 * p + 2];
        int ix = min((int)(xx * 8.0f), 7);
        int iy = min((int)(yy * 8.0f), 7);
        int iz = min((int)(zz * 8.0f), 7);
        int cid = (iz << 6) | (iy << 3) | ix;
        int slot = cellstart[cid] + atomicAdd(&coff[cid], 1);
        rx[slot] = xx; ry[slot] = yy; rz[slot] = zz;
        sridx[slot] = (unsigned short)p;
        smind[slot] = 1e30f;
    }
    cellmax[t] = 1e30f;                 // forces dense path on iter 0
    cellarg[t] = 0x7FFFFFFF;
    // this thread's cell box (multiples of 0.125 are exact in fp32)
    const float lox = (float)(t & 7) * 0.125f;
    const float loy = (float)((t >> 3) & 7) * 0.125f;
    const float loz = (float)(t >> 6) * 0.125f;
    __syncthreads();

    float lx = pb[0], ly = pb[1], lz = pb[2];   // first centroid = point 0

    for (int m = 0; m < MCENT; ++m) {
        if (t == 0) {
            float* o = pos_s + (b * MCENT + m) * 3;
            o[0] = lx; o[1] = ly; o[2] = lz;
        }
        if (m + 1 == MCENT) break;      // final argmax discarded by the scan

        // ---- A: per-cell lower bound + prune + ballot-compact survivors
        float cmx = cellmax[t];
        float dxm = fmaxf(fmaxf(lox - lx, lx - (lox + 0.125f)), 0.0f);
        float dym = fmaxf(fmaxf(loy - ly, ly - (loy + 0.125f)), 0.0f);
        float dzm = fmaxf(fmaxf(loz - lz, lz - (loz + 0.125f)), 0.0f);
        float lb2 = fmaf(dxm, dxm, fmaf(dym, dym, dzm * dzm)) * 0.9999f;
        bool sv = lb2 < cmx;
        unsigned long long mk = __ballot(sv);
        int base = 0;
        if (l == 0 && mk) base = atomicAdd(&s_nu, __popcll(mk));
        base = __builtin_amdgcn_readfirstlane(base);
        if (sv) clist[base + __popcll(mk & ((1ull << l) - 1ull))] = t;
        __syncthreads();                                    // b1
        const int NU = s_nu;

        if (NU > FPS_THRESH) {
            // ---- B-full: update all points (float4-wide), then all cells
            for (int i = 0; i < 4; ++i) {
                int g = (i << 9) + t;
                float4 fx = ((const float4*)rx)[g];
                float4 fy = ((const float4*)ry)[g];
                float4 fz = ((const float4*)rz)[g];
                float4 fm = ((const float4*)smind)[g];
                fm.x = fminf(fm.x, dist2(fx.x, fy.x, fz.x, lx, ly, lz));
                fm.y = fminf(fm.y, dist2(fx.y, fy.y, fz.y, lx, ly, lz));
                fm.z = fminf(fm.z, dist2(fx.z, fy.z, fz.z, lx, ly, lz));
                fm.w = fminf(fm.w, dist2(fx.w, fy.w, fz.w, lx, ly, lz));
                ((float4*)smind)[g] = fm;
            }
            __syncthreads();
            int s0 = cellstart[t], e0 = cellstart[t + 1];
            float red = -1.0f; int rarg = 0x7FFFFFFF;
            for (int j = s0; j < e0; ++j) {
                float mn = smind[j];
                int arg = (((int)sridx[j]) << 13) | j;
                bool tk = (mn > red) || (mn == red && arg < rarg);
                red = tk ? mn : red; rarg = tk ? arg : rarg;
            }
            cellmax[t] = red; cellarg[t] = rarg;
        } else {
            // ---- B-sparse: one QUARTER-WAVE (16 lanes) per surviving cell
            const int u  = t >> 4;      // quarter id 0..31
            const int lq = t & 15;
            for (int r = u; r < NU; r += 32) {
                int cid = clist[r];
                int s0 = cellstart[cid], e0 = cellstart[cid + 1];
                float red = -1.0f; int rarg = 0x7FFFFFFF;
                for (int j = s0 + lq; j < e0; j += 16) {
                    float d = dist2(rx[j], ry[j], rz[j], lx, ly, lz);
                    float mn = fminf(smind[j], d);
                    smind[j] = mn;
                    int arg = (((int)sridx[j]) << 13) | j;
                    bool tk = (mn > red) || (mn == red && arg < rarg);
                    red = tk ? mn : red; rarg = tk ? arg : rarg;
                }
                // 16-lane DPP argmax: all controls stay within one DPP row
#define ASTEP(C_) { float ov = dppf<C_>(red); int oa = dppi<C_>(rarg);        \
                    bool tk = (ov > red) || (ov == red && oa < rarg);         \
                    red = tk ? ov : red; rarg = tk ? oa : rarg; }
                ASTEP(0xB1)   // quad_perm xor1
                ASTEP(0x4E)   // quad_perm xor2
                ASTEP(0x141)  // row_half_mirror (xor7 within 8)
                ASTEP(0x140)  // row_mirror (xor15 within 16)
#undef ASTEP
                if (lq == 0) { cellmax[cid] = red; cellarg[cid] = rarg; }
            }
        }
        __syncthreads();                                    // b2

        // ---- C: block argmax over (cellmax, cellarg); tie -> min arg
        float bv = cellmax[t]; int ba = cellarg[t];
#define RSTEP(C_) { float ov = dppf<C_>(bv); int oa = dppi<C_>(ba);           \
                    bool tk = (ov > bv) || (ov == bv && oa < ba);             \
                    bv = tk ? ov : bv; ba = tk ? oa : ba; }
        RSTEP(0xB1) RSTEP(0x4E) RSTEP(0x141)
        RSTEP(0x140) RSTEP(0x142) RSTEP(0x143)
#undef RSTEP
        if (l == 63) { s_bv[w] = bv; s_ba[w] = ba; }
        if (t == 0) s_nu = 0;
        __syncthreads();                                    // b3
        float gv = s_bv[0]; int ga = s_ba[0];
#pragma unroll
        for (int q = 1; q < 8; ++q) {
            float ov = s_bv[q]; int oa = s_ba[q];
            bool tk = (ov > gv) || (ov == gv && oa < ga);
            gv = tk ? ov : gv; ga = tk ? oa : ga;
        }
        const int j = ga & 8191;        // winner coords: broadcast LDS reads
        lx = rx[j]; ly = ry[j]; lz = rz[j];
    }
}

// ---------------------------------------------------------------------------
// Kernel 2: exact top-64 (by (d2, idx) u64 key) within ball r=0.4 via
// histogram radix-select + O(C^2) exact ranking. (unchanged)
// ---------------------------------------------------------------------------
#define KNN_CAP 320

__global__ __launch_bounds__(256) void knn_kernel(const float* __restrict__ pos,
                                                  const float* __restrict__ pos_s,
                                                  int* __restrict__ nidx,
                                                  float* __restrict__ nd2,
                                                  int* __restrict__ ncnt) {
    const int c = blockIdx.x;
    const int b = c >> 11;              // c / MCENT
    const float* pb = pos + b * NPTS * 3;
    const int t = threadIdx.x;

    const float cx = pos_s[c * 3 + 0];
    const float cy = pos_s[c * 3 + 1];
    const float cz = pos_s[c * 3 + 2];

    __shared__ int hist[64];
    __shared__ int s_B64, s_total, s_cnt;
    __shared__ unsigned long long cand[KNN_CAP];

    if (t < 64) hist[t] = 0;
    if (t == 0) s_cnt = 0;
    __syncthreads();

    float d2r[32];
#pragma unroll
    for (int i = 0; i < 32; ++i) {
        int p = (i << 8) + t;
        float d2 = dist2(cx, cy, cz, pb[3 * p + 0], pb[3 * p + 1], pb[3 * p + 2]);
        d2r[i] = d2;
        if (d2 <= 0.16f) {
            int bkt = (int)(d2 * 400.0f);      // monotone; 0.16f*400 < 64
            bkt = bkt > 63 ? 63 : bkt;
            atomicAdd(&hist[bkt], 1);
        }
    }
    __syncthreads();

    if (t == 0) {
        int cum = 0, B = -1;
#pragma unroll
        for (int j = 0; j < 64; ++j) {
            cum += hist[j];
            if (B < 0 && cum >= 64) B = j;
        }
        s_B64 = (B < 0) ? 63 : B;
        s_total = cum;
    }
    __syncthreads();

    const int B64 = s_B64;
#pragma unroll
    for (int i = 0; i < 32; ++i) {
        float d2 = d2r[i];
        if (d2 <= 0.16f) {
            int bkt = (int)(d2 * 400.0f);
            bkt = bkt > 63 ? 63 : bkt;
            if (bkt <= B64) {
                int slot = atomicAdd(&s_cnt, 1);
                if (slot < KNN_CAP) {
                    int p = (i << 8) + t;
                    cand[slot] = ((unsigned long long)__float_as_uint(d2) << 32)
                                 | (unsigned int)p;
                }
            }
        }
    }
    __syncthreads();

    const int C = s_cnt < KNN_CAP ? s_cnt : KNN_CAP;
    for (int tc = t; tc < C; tc += 256) {
        unsigned long long my = cand[tc];
        int rank = 0;
        for (int j = 0; j < C; ++j) rank += (cand[j] < my) ? 1 : 0;
        if (rank < KMAX) {
            nidx[c * KMAX + rank] = (int)(my & 0xffffffffULL);
            nd2[c * KMAX + rank]  = __uint_as_float((unsigned int)(my >> 32));
        }
    }
    if (t == 0) ncnt[c] = s_total < KMAX ? s_total : KMAX;
}

// ---------------------------------------------------------------------------
// Kernel 3: fused gather + 2-layer MLP + masked max per centroid. (unchanged)
// ---------------------------------------------------------------------------
template <int K, int C1, int C2, int OUTOFF>
__global__ __launch_bounds__(256, 2) void mlp_kernel(
        const float* __restrict__ x, const float* __restrict__ pos,
        const float* __restrict__ pos_s,
        const int* __restrict__ nidx, const float* __restrict__ nd2,
        const int* __restrict__ ncnt,
        const float* __restrict__ W1, const float* __restrict__ B1,
        const float* __restrict__ W2, const float* __restrict__ B2,
        float* __restrict__ out, float r2) {
    const int c = blockIdx.x;
    const int b = c >> 11;
    const int t = threadIdx.x;

    __shared__ float F[K][68];      // [K][67] padded to 17 float4
    __shared__ float H[K][C1];
    __shared__ int   s_nbr[K];
    __shared__ int   s_valid[K];
    __shared__ float s_ctr[3];

    const int cntAll = ncnt[c];
    const int cnt = cntAll < K ? cntAll : K;
    if (t < 3) s_ctr[t] = pos_s[c * 3 + t];
    if (t < K) {
        bool ok = t < cnt;
        s_nbr[t]   = ok ? nidx[c * KMAX + t] : 0;
        s_valid[t] = ok && (nd2[c * KMAX + t] <= r2);
    }
    __syncthreads();

    // gather features: F[k] = [ x[nbr] (64) | pos[nbr]-ctr (3) | 0 pad ]
    for (int e = t; e < K * 17; e += 256) {
        int k = e / 17, q = e % 17;
        int nbr = s_nbr[k];
        bool ok = k < cnt;
        float4 val;
        if (q < 16) {
            const float4* xr = (const float4*)(x + (b * NPTS + nbr) * CFEAT);
            if (ok) val = xr[q];
            else { val.x = 0.f; val.y = 0.f; val.z = 0.f; val.w = 0.f; }
        } else {
            const float* pp = pos + (b * NPTS + nbr) * 3;
            val.x = ok ? pp[0] - s_ctr[0] : 0.f;
            val.y = ok ? pp[1] - s_ctr[1] : 0.f;
            val.z = ok ? pp[2] - s_ctr[2] : 0.f;
            val.w = 0.f;
        }
        ((float4*)&F[k][0])[q] = val;
    }
    __syncthreads();

    // layer 1: H[k][j] = relu(B1[j] + F[k]·W1[:,j])
    {
        constexpr int STR = 256 / C1;
        const int j  = t % C1;
        const int kb = t / C1;
        float w1c[68];
#pragma unroll
        for (int i = 0; i < 67; ++i) w1c[i] = W1[i * C1 + j];
        w1c[67] = 0.f;
        const float bj = B1[j];
        for (int k = kb; k < K; k += STR) {
            float acc = bj;
            const float4* fr = (const float4*)&F[k][0];
#pragma unroll
            for (int q = 0; q < 17; ++q) {
                float4 f = fr[q];
                acc = fmaf(f.x, w1c[4 * q + 0], acc);
                acc = fmaf(f.y, w1c[4 * q + 1], acc);
                acc = fmaf(f.z, w1c[4 * q + 2], acc);
                acc = fmaf(f.w, w1c[4 * q + 3], acc);
            }
            H[k][j] = fmaxf(acc, 0.f);
        }
    }
    __syncthreads();

    // layer 2 + masked max over neighbors
    if constexpr (C2 == 256) {
        const int j2 = t;
        float w2c[C1];
#pragma unroll
        for (int i = 0; i < C1; ++i) w2c[i] = W2[i * C2 + j2];
        const float bj = B2[j2];
        float omax = NEGV;
        for (int k = 0; k < K; ++k) {
            if (!s_valid[k]) continue;          // uniform branch
            float acc = bj;
            const float4* hr = (const float4*)&H[k][0];
#pragma unroll
            for (int q = 0; q < C1 / 4; ++q) {
                float4 h = hr[q];
                acc = fmaf(h.x, w2c[4 * q + 0], acc);
                acc = fmaf(h.y, w2c[4 * q + 1], acc);
                acc = fmaf(h.z, w2c[4 * q + 2], acc);
                acc = fmaf(h.w, w2c[4 * q + 3], acc);
            }
            omax = fmaxf(omax, fmaxf(acc, 0.f));
        }
        out[c * 384 + OUTOFF + j2] = omax;
    } else {
        // C2 == 128: 2 thread-groups split the k range, combine via LDS
        const int j2 = t % C2;
        const int g  = t / C2;
        __shared__ float pm[256];
        float w2c[C1];
#pragma unroll
        for (int i = 0; i < C1; ++i) w2c[i] = W2[i * C2 + j2];
        const float bj = B2[j2];
        float omax = NEGV;
        for (int k = g; k < K; k += 2) {
            if (!s_valid[k]) continue;
            float acc = bj;
            const float4* hr = (const float4*)&H[k][0];
#pragma unroll
            for (int q = 0; q < C1 / 4; ++q) {
                float4 h = hr[q];
                acc = fmaf(h.x, w2c[4 * q + 0], acc);
                acc = fmaf(h.y, w2c[4 * q + 1], acc);
                acc = fmaf(h.z, w2c[4 * q + 2], acc);
                acc = fmaf(h.w, w2c[4 * q + 3], acc);
            }
            omax = fmaxf(omax, fmaxf(acc, 0.f));
        }
        pm[t] = omax;
        __syncthreads();
        if (t < C2) out[c * 384 + OUTOFF + t] = fmaxf(pm[t], pm[t + C2]);
    }
}

extern "C" void kernel_launch(void* const* d_in, const int* in_sizes, int n_in,
                              void* d_out, int out_size, void* d_ws, size_t ws_size,
                              hipStream_t stream) {
    const float* x    = (const float*)d_in[0];
    const float* pos  = (const float*)d_in[1];
    const float* w1_0 = (const float*)d_in[2];
    const float* b1_0 = (const float*)d_in[3];
    const float* w1_1 = (const float*)d_in[4];
    const float* b1_1 = (const float*)d_in[5];
    const float* w2_0 = (const float*)d_in[6];
    const float* b2_0 = (const float*)d_in[7];
    const float* w2_1 = (const float*)d_in[8];
    const float* b2_1 = (const float*)d_in[9];

    float* out   = (float*)d_out;
    float* pos_s = out + NCENT * 384;          // second output, written by FPS

    char* ws = (char*)d_ws;
    int*   ncnt = (int*)ws;                                   // NCENT ints
    int*   nidx = (int*)(ws + NCENT * 4);                     // NCENT*64 ints
    float* nd2  = (float*)(ws + NCENT * 4 + NCENT * KMAX * 4);// NCENT*64 floats

    fps_kernel<<<BATCH, FPS_T, 0, stream>>>(pos, pos_s);
    knn_kernel<<<NCENT, 256, 0, stream>>>(pos, pos_s, nidx, nd2, ncnt);
    mlp_kernel<32, 64, 128, 0><<<NCENT, 256, 0, stream>>>(
        x, pos, pos_s, nidx, nd2, ncnt, w1_0, b1_0, w1_1, b1_1, out, 0.04f);
    mlp_kernel<64, 128, 256, 128><<<NCENT, 256, 0, stream>>>(
        x, pos, pos_s, nidx, nd2, ncnt, w2_0, b2_0, w2_1, b2_1, out, 0.16f);
}